// Round 7
// baseline (340.618 us; speedup 1.0000x reference)
//
#include <hip/hip_runtime.h>
#include <hip/hip_bf16.h>

typedef short short8 __attribute__((ext_vector_type(8)));
typedef float f32x4 __attribute__((ext_vector_type(4)));

#define S_   64
#define NL_  5000
#define PD_  1024
#define LD_  768
#define DIM_ 512
#define OD_  512

#define BK     32
#define KSTEPS 16          // DIM_/BK
#define NT_M   79          // ceil(5000/64) n-tiles for main
#define HL_RT  157         // ceil(5000/32) row-tiles for hl

// LDS layout (bytes): [A0 8K][A1 8K][B0 32K][B1 32K][B2 32K][hp 4K] = 116K
#define BOFF   16384
#define HPOFF  (16384 + 3 * 32768)

__device__ __forceinline__ ushort f2bf(float f) {
    union { float f; unsigned u; } v; v.f = f;
    unsigned r = v.u + 0x7fffu + ((v.u >> 16) & 1u);   // RNE
    return (ushort)(r >> 16);
}
__device__ __forceinline__ float bf2f(ushort h) {
    union { unsigned u; float f; } v; v.u = ((unsigned)h) << 16;
    return v.f;
}
// XOR swizzle for 64B-stride row tiles (conflict-free write/read; bijective).
__device__ __forceinline__ int swz(int row, int kslot) {
    return (row * 64 + kslot * 16) ^ (((row >> 1) & 7) << 4);
}
__device__ __forceinline__ void glds16(const void* g, void* l) {
    __builtin_amdgcn_global_load_lds(
        (const __attribute__((address_space(1))) void*)g,
        (__attribute__((address_space(3))) void*)l, 16, 0, 0);
}

#define LGKM0 do { asm volatile("s_waitcnt lgkmcnt(0)" ::: "memory"); \
                   __builtin_amdgcn_sched_barrier(0); } while (0)
#define BARRIER __builtin_amdgcn_s_barrier()

#define MFMA_HALF(OFS) \
  _Pragma("unroll") \
  for (int mt = 0; mt < 4; ++mt) { \
    acc[mt][(OFS)+0] = __builtin_amdgcn_mfma_f32_16x16x32_bf16(Ar[mt], Br[0], acc[mt][(OFS)+0], 0, 0, 0); \
    acc[mt][(OFS)+1] = __builtin_amdgcn_mfma_f32_16x16x32_bf16(Ar[mt], Br[1], acc[mt][(OFS)+1], 0, 0, 0); \
    acc[mt][(OFS)+2] = __builtin_amdgcn_mfma_f32_16x16x32_bf16(Ar[mt], Br[2], acc[mt][(OFS)+2], 0, 0, 0); \
    acc[mt][(OFS)+3] = __builtin_amdgcn_mfma_f32_16x16x32_bf16(Ar[mt], Br[3], acc[mt][(OFS)+3], 0, 0, 0); \
  }

// ==== pre-pass 1: {W2 panel prep | M_lT | P_e = P_f @ W_p.T} ================
__global__ __launch_bounds__(256) void k_pre1(
    const float* __restrict__ W2, const float* __restrict__ W_l,
    const float* __restrict__ W1, const float* __restrict__ P_f,
    const float* __restrict__ W_p,
    char* __restrict__ panel, ushort* __restrict__ MlT, float* __restrict__ P_e) {
    __shared__ float w1r[8][DIM_];
    int b = blockIdx.x, t = threadIdx.x;
    if (b < 128) {
        int c = b * 256 + t;                   // 32768 16B-chunks
        int o = c >> 6, rem = c & 63, kt = rem >> 2, kslot = rem & 3;
        const float* src = W2 + o * DIM_ + kt * BK + kslot * 8;
        float4 v0 = *(const float4*)src;
        float4 v1 = *(const float4*)(src + 4);
        union { ushort u[8]; short8 v; } pk;
        pk.u[0] = f2bf(v0.x); pk.u[1] = f2bf(v0.y); pk.u[2] = f2bf(v0.z); pk.u[3] = f2bf(v0.w);
        pk.u[4] = f2bf(v1.x); pk.u[5] = f2bf(v1.y); pk.u[6] = f2bf(v1.z); pk.u[7] = f2bf(v1.w);
        *(short8*)(panel + kt * 32768 + swz(o, kslot)) = pk.v;
    } else if (b < 320) {
        int bx = b - 128;
        int o0 = (bx / 3) * 8;
        int ld = (bx % 3) * 256 + t;
        for (int i = t; i < 8 * DIM_; i += 256)
            w1r[i >> 9][i & 511] = W1[(o0 + (i >> 9)) * (2 * DIM_) + DIM_ + (i & 511)];
        __syncthreads();
        float acc[8] = {};
        for (int dim = 0; dim < DIM_; dim++) {
            float wl = W_l[dim * LD_ + ld];
#pragma unroll
            for (int oi = 0; oi < 8; oi++) acc[oi] += w1r[oi][dim] * wl;
        }
#pragma unroll
        for (int oi = 0; oi < 8; oi++) MlT[(o0 + oi) * LD_ + ld] = f2bf(acc[oi]);
    } else {
        int o = b - 320;
        int s = t >> 2, kk = t & 3;
        const float* a = P_f + s * PD_ + kk * 256;
        const float* w = W_p + (size_t)o * PD_ + kk * 256;
        float acc = 0.f;
        for (int k = 0; k < 256; k += 4) {
            float4 av = *(const float4*)(a + k);
            float4 wv = *(const float4*)(w + k);
            acc += av.x * wv.x + av.y * wv.y + av.z * wv.z + av.w * wv.w;
        }
        acc += __shfl_xor(acc, 1, 64);
        acc += __shfl_xor(acc, 2, 64);
        if (kk == 0) P_e[s * DIM_ + o] = acc;
    }
}

// ==== pre-pass 2: {hpb = P_e @ W1p.T + b1 | hlB = bf16(emb[L]) @ MlT} =======
__global__ __launch_bounds__(256) void k_pre2(
    const float* __restrict__ P_e, const float* __restrict__ W1,
    const float* __restrict__ b1, const float* __restrict__ emb,
    const int* __restrict__ L, const ushort* __restrict__ MlT,
    float* __restrict__ hpb, ushort* __restrict__ hlB) {
    int b = blockIdx.x, t = threadIdx.x;
    if (b < 512) {
        int o = b;
        int s = t >> 2, kk = t & 3;
        const float* a = P_e + s * DIM_ + kk * 128;
        const float* w = W1 + (size_t)o * (2 * DIM_) + kk * 128;
        float acc = 0.f;
        for (int k = 0; k < 128; k += 4) {
            float4 av = *(const float4*)(a + k);
            float4 wv = *(const float4*)(w + k);
            acc += av.x * wv.x + av.y * wv.y + av.z * wv.z + av.w * wv.w;
        }
        acc += __shfl_xor(acc, 1, 64);
        acc += __shfl_xor(acc, 2, 64);
        if (kk == 0) hpb[s * DIM_ + o] = acc + b1[o];
    } else {
        int hb = b - 512;                     // 0..313
        int rblk = hb % HL_RT, oh = hb / HL_RT;
        int r0 = rblk * 32;
        int w = t >> 6, l = t & 63, lg = l >> 4, ll = l & 15;
        const float* arow[2];
#pragma unroll
        for (int mt = 0; mt < 2; mt++) {
            int r = r0 + mt * 16 + ll;
            if (r >= NL_) r = NL_ - 1;
            arow[mt] = emb + (size_t)L[r] * LD_ + lg * 8;
        }
        f32x4 acc[2][4] = {};
        for (int k = 0; k < LD_; k += 32) {
            short8 a[2], bf[4];
#pragma unroll
            for (int mt = 0; mt < 2; mt++) {
                float4 v0 = *(const float4*)(arow[mt] + k);
                float4 v1 = *(const float4*)(arow[mt] + k + 4);
                union { ushort u[8]; short8 v; } pk;
                pk.u[0] = f2bf(v0.x); pk.u[1] = f2bf(v0.y);
                pk.u[2] = f2bf(v0.z); pk.u[3] = f2bf(v0.w);
                pk.u[4] = f2bf(v1.x); pk.u[5] = f2bf(v1.y);
                pk.u[6] = f2bf(v1.z); pk.u[7] = f2bf(v1.w);
                a[mt] = pk.v;
            }
#pragma unroll
            for (int ot = 0; ot < 4; ot++) {
                int o = oh * 256 + w * 64 + ot * 16 + ll;
                bf[ot] = *(const short8*)(MlT + o * LD_ + k + lg * 8);
            }
#pragma unroll
            for (int mt = 0; mt < 2; mt++)
#pragma unroll
                for (int ot = 0; ot < 4; ot++)
                    acc[mt][ot] = __builtin_amdgcn_mfma_f32_16x16x32_bf16(a[mt], bf[ot], acc[mt][ot], 0, 0, 0);
        }
#pragma unroll
        for (int mt = 0; mt < 2; mt++)
#pragma unroll
            for (int ot = 0; ot < 4; ot++)
#pragma unroll
                for (int reg = 0; reg < 4; reg++) {
                    int r = r0 + mt * 16 + lg * 4 + reg;
                    if (r < NL_)
                        hlB[(size_t)r * DIM_ + oh * 256 + w * 64 + ot * 16 + ll] = f2bf(acc[mt][ot][reg]);
                }
    }
}

// ==== main: BM=128 x BN=512, 8-phase schedule (T2+T3+T4+T5 port) ============
// 8 waves (2M x 4N), wave tile 64x128, acc[4][8] (AGPR).
// Iteration = 2 k-steps (K=64), 4 phases; each phase:
//   {ds-reads for THIS phase's MFMA | 2 glds stage | (packA/hl/vmcnt)}
//   -> BAR -> lgkmcnt(0) -> setprio(1) -> 16 MFMA -> setprio(0) -> BAR
// Counted vmcnt only at P2/P4 (6/6 steady; 5/4 at i=6; 0 at i=7).
// Hazards: every LDS buffer's reads drain at the reader's lgkmcnt(0) right
// after BAR#1 of their phase -> block-wide complete by that phase's end-BAR;
// all writers (glds stage, packA ds_write) issue >=1 full phase later.
__global__ __launch_bounds__(512, 2) void k_main2(
    const ushort* __restrict__ hlB, const float* __restrict__ hpb,
    const char* __restrict__ panel, const float* __restrict__ b2,
    const float* __restrict__ W3, const float* __restrict__ b3,
    float* __restrict__ out) {
    __shared__ f32x4 ldsv[7424];            // 118784 B
    char* lds = (char*)ldsv;
    const int t = threadIdx.x;
    const int n0 = blockIdx.x * 64, s0 = blockIdx.y * 2;
    const int w = t >> 6, lane = t & 63, lg = lane >> 4, ll = lane & 15;
    const int wr = w >> 2, wc = w & 3;      // 2M x 4N wave grid

    // A-staging ids: thread t owns one 16B chunk (row = t>>2, kslot = t&3)
    const int arow = t >> 2, akslot = t & 3;
    int an = n0 + (arow & 63); if (an >= NL_) an = NL_ - 1;
    const ushort* hlsrc = hlB + (size_t)an * DIM_ + akslot * 8;
    const int awz = swz(arow, akslot);

    int aoffS[4], boffS[8];
#pragma unroll
    for (int mt = 0; mt < 4; mt++) aoffS[mt] = swz(wr * 64 + mt * 16 + ll, lg);
#pragma unroll
    for (int ot = 0; ot < 8; ot++) boffS[ot] = swz(wc * 128 + ot * 16 + ll, lg);

    f32x4 acc[4][8] = {};

    // stage half a B k-tile: 2 glds/thread (wave-uniform LDS dest + lane*16)
    auto stage2 = [&](int kt, int half) {
        const char* base = panel + kt * 32768 + w * 4096 + half * 2048 + (lane << 4);
        char* dst = lds + BOFF + (kt % 3) * 32768 + w * 4096 + half * 2048;
        glds16(base, dst);
        glds16(base + 1024, dst + 1024);
    };
    // pack A k-tile kt: hl from reg, hp slice from LDS table
    auto packA2 = [&](int kt, short8 hv) {
        const char* hpp = lds + HPOFF + (arow >> 6) * 2048 + kt * 128 + akslot * 32;
        f32x4 p0 = *(const f32x4*)(hpp);
        f32x4 p1 = *(const f32x4*)(hpp + 16);
        float hp8[8] = { p0[0], p0[1], p0[2], p0[3], p1[0], p1[1], p1[2], p1[3] };
        float x[8];
#pragma unroll
        for (int e = 0; e < 8; e++) {
            float s = bf2f((ushort)hv[e]) + hp8[e];
            x[e] = s > 0.f ? s : 0.f;
        }
        union { __hip_bfloat162 h2[4]; short8 v; } pk;
#pragma unroll
        for (int e = 0; e < 4; e++)
            pk.h2[e] = __float22bfloat162_rn(make_float2(x[2 * e], x[2 * e + 1]));
        *(short8*)(lds + (kt & 1) * 8192 + awz) = pk.v;
    };

    // ---- prologue: stage B[0],B[1], hp table, hl(0..3); pack A(0),A(1) ----
    short8 hlp0, hlp1;
    {
        stage2(0, 0); stage2(0, 1);
        stage2(1, 0); stage2(1, 1);
        if (w < 4)  // hp table: 4KB linear copy (hpb rows s0,s0+1 with +b1)
            glds16((const char*)(hpb + s0 * DIM_) + w * 1024 + (lane << 4),
                   lds + HPOFF + w * 1024);
        short8 hl0 = *(const short8*)(hlsrc);
        short8 hl1 = *(const short8*)(hlsrc + BK);
        hlp0 = *(const short8*)(hlsrc + 2 * BK);
        hlp1 = *(const short8*)(hlsrc + 3 * BK);
        asm volatile("s_waitcnt vmcnt(0) lgkmcnt(0)" ::: "memory");
        __builtin_amdgcn_sched_barrier(0);
        BARRIER;
        packA2(0, hl0);
        packA2(1, hl1);
        LGKM0;
        BARRIER;
    }

#pragma unroll 1
    for (int i = 0; i < 8; ++i) {
        const int k0 = 2 * i, k1 = k0 + 1;
        const char* Bb0 = lds + BOFF + (k0 % 3) * 32768;
        const char* Bb1 = lds + BOFF + (k1 % 3) * 32768;
        short8 Ar[4], Br[4];
        // ===== P1: A(k0) + B(k0).lo =====
#pragma unroll
        for (int mt = 0; mt < 4; mt++) Ar[mt] = *(const short8*)(lds + aoffS[mt]);
#pragma unroll
        for (int j = 0; j < 4; j++) Br[j] = *(const short8*)(Bb0 + boffS[j]);
        if (i < 7) stage2(k0 + 2, 0);
        BARRIER; LGKM0;
        __builtin_amdgcn_s_setprio(1);
        MFMA_HALF(0)
        __builtin_amdgcn_s_setprio(0);
        BARRIER;
        // ===== P2: A(k0) + B(k0).hi; pack A(k0+2); vmcnt =====
        if (i < 7) { stage2(k0 + 2, 1); packA2(k0 + 2, hlp0); }
#pragma unroll
        for (int j = 0; j < 4; j++) Br[j] = *(const short8*)(Bb0 + boffS[4 + j]);
        if (i < 6) hlp0 = *(const short8*)(hlsrc + (k0 + 4) * BK);
        if (i < 6)      asm volatile("s_waitcnt vmcnt(6)" ::: "memory");
        else if (i == 6) asm volatile("s_waitcnt vmcnt(5)" ::: "memory");
        else            asm volatile("s_waitcnt vmcnt(0)" ::: "memory");
        BARRIER; LGKM0;
        __builtin_amdgcn_s_setprio(1);
        MFMA_HALF(4)
        __builtin_amdgcn_s_setprio(0);
        BARRIER;
        // ===== P3: A(k1) + B(k1).lo =====
#pragma unroll
        for (int mt = 0; mt < 4; mt++) Ar[mt] = *(const short8*)(lds + 8192 + aoffS[mt]);
#pragma unroll
        for (int j = 0; j < 4; j++) Br[j] = *(const short8*)(Bb1 + boffS[j]);
        if (i < 7) stage2(k1 + 2, 0);
        BARRIER; LGKM0;
        __builtin_amdgcn_s_setprio(1);
        MFMA_HALF(0)
        __builtin_amdgcn_s_setprio(0);
        BARRIER;
        // ===== P4: A(k1) + B(k1).hi; pack A(k1+2); vmcnt =====
        if (i < 7) { stage2(k1 + 2, 1); packA2(k1 + 2, hlp1); }
#pragma unroll
        for (int j = 0; j < 4; j++) Br[j] = *(const short8*)(Bb1 + boffS[4 + j]);
        if (i < 6) hlp1 = *(const short8*)(hlsrc + (k1 + 4) * BK);
        if (i < 6)      asm volatile("s_waitcnt vmcnt(6)" ::: "memory");
        else if (i == 6) asm volatile("s_waitcnt vmcnt(4)" ::: "memory");
        BARRIER; LGKM0;
        __builtin_amdgcn_s_setprio(1);
        MFMA_HALF(4)
        __builtin_amdgcn_s_setprio(0);
        BARRIER;
    }

    // ---- epilogue: relu(acc+b2)*W3, reduce over o; direct out write ----
    float* logit = (float*)lds;                           // reuse A buf 0
    if (t < 128) logit[t] = 0.f;
    __syncthreads();
#pragma unroll
    for (int mt = 0; mt < 4; mt++) {
        float p4[4] = { 0.f, 0.f, 0.f, 0.f };
#pragma unroll
        for (int ot = 0; ot < 8; ot++) {
            int o = wc * 128 + ot * 16 + ll;
            float bb = b2[o], w3 = W3[o];
#pragma unroll
            for (int reg = 0; reg < 4; reg++) {
                float v = acc[mt][ot][reg] + bb;
                v = v > 0.f ? v : 0.f;
                p4[reg] += v * w3;
            }
        }
#pragma unroll
        for (int m = 1; m < 16; m <<= 1)
#pragma unroll
            for (int reg = 0; reg < 4; reg++) p4[reg] += __shfl_xor(p4[reg], m, 64);
        if (ll == 0)
#pragma unroll
            for (int reg = 0; reg < 4; reg++)
                atomicAdd(&logit[wr * 64 + mt * 16 + lg * 4 + reg], p4[reg]);
    }
    __syncthreads();
    if (t < 128) {
        int n = n0 + (t & 63);
        int s = s0 + (t >> 6);
        if (n < NL_) out[(size_t)s * NL_ + n] = logit[t] + b3[0];
    }
}

extern "C" void kernel_launch(void* const* d_in, const int* in_sizes, int n_in,
                              void* d_out, int out_size, void* d_ws, size_t ws_size,
                              hipStream_t stream) {
    const float* P_f = (const float*)d_in[0];
    const float* emb = (const float*)d_in[1];
    const float* W_p = (const float*)d_in[2];
    const float* W_l = (const float*)d_in[3];
    const float* W1  = (const float*)d_in[4];
    const float* b1  = (const float*)d_in[5];
    const float* W2  = (const float*)d_in[6];
    const float* b2  = (const float*)d_in[7];
    const float* W3  = (const float*)d_in[8];
    const float* b3  = (const float*)d_in[9];
    const int*   L   = (const int*)d_in[10];
    float* out = (float*)d_out;

    char* ws = (char*)d_ws;
    size_t off = 0;
    auto alloc = [&](size_t bytes) {
        void* p = ws + off;
        off = (off + bytes + 255) & ~(size_t)255;
        return p;
    };
    char*   panel = (char*)alloc((size_t)KSTEPS * 32768);            // 512 KB
    ushort* MlT   = (ushort*)alloc((size_t)OD_ * LD_ * 2);           // 768 KB
    float*  P_e   = (float*)alloc((size_t)S_ * DIM_ * 4);
    float*  hpb   = (float*)alloc((size_t)S_ * DIM_ * 4);
    ushort* hlB   = (ushort*)alloc((size_t)NL_ * DIM_ * 2);          // 5.12 MB

    k_pre1<<<832, 256, 0, stream>>>(W2, W_l, W1, P_f, W_p, panel, MlT, P_e);
    k_pre2<<<826, 256, 0, stream>>>(P_e, W1, b1, emb, L, MlT, hpb, hlB);
    k_main2<<<dim3(NT_M, 32), 512, 0, stream>>>(hlB, hpb, panel, b2, W3, b3, out);
}

// Round 8
// 339.318 us; speedup vs baseline: 1.0038x; 1.0038x over previous
//
#include <hip/hip_runtime.h>
#include <hip/hip_bf16.h>

typedef short short8 __attribute__((ext_vector_type(8)));
typedef float f32x4 __attribute__((ext_vector_type(4)));
typedef float f32x16 __attribute__((ext_vector_type(16)));

#define S_   64
#define NL_  5000
#define PD_  1024
#define LD_  768
#define DIM_ 512
#define OD_  512

#define BK     32
#define KSTEPS 16          // DIM_/BK
#define NT_M   79          // ceil(5000/64) n-tiles for main
#define HL_RT  157         // ceil(5000/32) row-tiles for hl

__device__ __forceinline__ ushort f2bf(float f) {
    union { float f; unsigned u; } v; v.f = f;
    unsigned r = v.u + 0x7fffu + ((v.u >> 16) & 1u);   // RNE
    return (ushort)(r >> 16);
}
__device__ __forceinline__ float bf2f(ushort h) {
    union { unsigned u; float f; } v; v.u = ((unsigned)h) << 16;
    return v.f;
}
// XOR swizzle for 64B-stride row tiles; bijective; conflict-free for the
// packA write (4 lanes/row x 4 kslots), the 16-row read (r6, measured 0)
// and the 32-row x fixed-kslot read (32x32 frags; slot8 uniformity checked).
__device__ __forceinline__ int swz(int row, int kslot) {
    return (row * 64 + kslot * 16) ^ (((row >> 1) & 7) << 4);
}
__device__ __forceinline__ void glds16(const void* g, void* l) {
    __builtin_amdgcn_global_load_lds(
        (const __attribute__((address_space(1))) void*)g,
        (__attribute__((address_space(3))) void*)l, 16, 0, 0);
}

// ==== pre-pass 1: {W2 panel prep | M_lT | P_e = P_f @ W_p.T} ================
__global__ __launch_bounds__(256) void k_pre1(
    const float* __restrict__ W2, const float* __restrict__ W_l,
    const float* __restrict__ W1, const float* __restrict__ P_f,
    const float* __restrict__ W_p,
    char* __restrict__ panel, ushort* __restrict__ MlT, float* __restrict__ P_e) {
    __shared__ float w1r[8][DIM_];
    int b = blockIdx.x, t = threadIdx.x;
    if (b < 128) {
        int c = b * 256 + t;                   // 32768 16B-chunks
        int o = c >> 6, rem = c & 63, kt = rem >> 2, kslot = rem & 3;
        const float* src = W2 + o * DIM_ + kt * BK + kslot * 8;
        float4 v0 = *(const float4*)src;
        float4 v1 = *(const float4*)(src + 4);
        union { ushort u[8]; short8 v; } pk;
        pk.u[0] = f2bf(v0.x); pk.u[1] = f2bf(v0.y); pk.u[2] = f2bf(v0.z); pk.u[3] = f2bf(v0.w);
        pk.u[4] = f2bf(v1.x); pk.u[5] = f2bf(v1.y); pk.u[6] = f2bf(v1.z); pk.u[7] = f2bf(v1.w);
        *(short8*)(panel + kt * 32768 + swz(o, kslot)) = pk.v;
    } else if (b < 320) {
        int bx = b - 128;
        int o0 = (bx / 3) * 8;
        int ld = (bx % 3) * 256 + t;
        for (int i = t; i < 8 * DIM_; i += 256)
            w1r[i >> 9][i & 511] = W1[(o0 + (i >> 9)) * (2 * DIM_) + DIM_ + (i & 511)];
        __syncthreads();
        float acc[8] = {};
        for (int dim = 0; dim < DIM_; dim++) {
            float wl = W_l[dim * LD_ + ld];
#pragma unroll
            for (int oi = 0; oi < 8; oi++) acc[oi] += w1r[oi][dim] * wl;
        }
#pragma unroll
        for (int oi = 0; oi < 8; oi++) MlT[(o0 + oi) * LD_ + ld] = f2bf(acc[oi]);
    } else {
        int o = b - 320;
        int s = t >> 2, kk = t & 3;
        const float* a = P_f + s * PD_ + kk * 256;
        const float* w = W_p + (size_t)o * PD_ + kk * 256;
        float acc = 0.f;
        for (int k = 0; k < 256; k += 4) {
            float4 av = *(const float4*)(a + k);
            float4 wv = *(const float4*)(w + k);
            acc += av.x * wv.x + av.y * wv.y + av.z * wv.z + av.w * wv.w;
        }
        acc += __shfl_xor(acc, 1, 64);
        acc += __shfl_xor(acc, 2, 64);
        if (kk == 0) P_e[s * DIM_ + o] = acc;
    }
}

// ==== pre-pass 2: {hpb = P_e @ W1p.T + b1 | hlB = bf16(emb[L]) @ MlT} =======
__global__ __launch_bounds__(256) void k_pre2(
    const float* __restrict__ P_e, const float* __restrict__ W1,
    const float* __restrict__ b1, const float* __restrict__ emb,
    const int* __restrict__ L, const ushort* __restrict__ MlT,
    float* __restrict__ hpb, ushort* __restrict__ hlB) {
    int b = blockIdx.x, t = threadIdx.x;
    if (b < 512) {
        int o = b;
        int s = t >> 2, kk = t & 3;
        const float* a = P_e + s * DIM_ + kk * 128;
        const float* w = W1 + (size_t)o * (2 * DIM_) + kk * 128;
        float acc = 0.f;
        for (int k = 0; k < 128; k += 4) {
            float4 av = *(const float4*)(a + k);
            float4 wv = *(const float4*)(w + k);
            acc += av.x * wv.x + av.y * wv.y + av.z * wv.z + av.w * wv.w;
        }
        acc += __shfl_xor(acc, 1, 64);
        acc += __shfl_xor(acc, 2, 64);
        if (kk == 0) hpb[s * DIM_ + o] = acc + b1[o];
    } else {
        int hb = b - 512;                     // 0..313
        int rblk = hb % HL_RT, oh = hb / HL_RT;
        int r0 = rblk * 32;
        int w = t >> 6, l = t & 63, lg = l >> 4, ll = l & 15;
        const float* arow[2];
#pragma unroll
        for (int mt = 0; mt < 2; mt++) {
            int r = r0 + mt * 16 + ll;
            if (r >= NL_) r = NL_ - 1;
            arow[mt] = emb + (size_t)L[r] * LD_ + lg * 8;
        }
        f32x4 acc[2][4] = {};
        for (int k = 0; k < LD_; k += 32) {
            short8 a[2], bf[4];
#pragma unroll
            for (int mt = 0; mt < 2; mt++) {
                float4 v0 = *(const float4*)(arow[mt] + k);
                float4 v1 = *(const float4*)(arow[mt] + k + 4);
                union { ushort u[8]; short8 v; } pk;
                pk.u[0] = f2bf(v0.x); pk.u[1] = f2bf(v0.y);
                pk.u[2] = f2bf(v0.z); pk.u[3] = f2bf(v0.w);
                pk.u[4] = f2bf(v1.x); pk.u[5] = f2bf(v1.y);
                pk.u[6] = f2bf(v1.z); pk.u[7] = f2bf(v1.w);
                a[mt] = pk.v;
            }
#pragma unroll
            for (int ot = 0; ot < 4; ot++) {
                int o = oh * 256 + w * 64 + ot * 16 + ll;
                bf[ot] = *(const short8*)(MlT + o * LD_ + k + lg * 8);
            }
#pragma unroll
            for (int mt = 0; mt < 2; mt++)
#pragma unroll
                for (int ot = 0; ot < 4; ot++)
                    acc[mt][ot] = __builtin_amdgcn_mfma_f32_16x16x32_bf16(a[mt], bf[ot], acc[mt][ot], 0, 0, 0);
        }
#pragma unroll
        for (int mt = 0; mt < 2; mt++)
#pragma unroll
            for (int ot = 0; ot < 4; ot++)
#pragma unroll
                for (int reg = 0; reg < 4; reg++) {
                    int r = r0 + mt * 16 + lg * 4 + reg;
                    if (r < NL_)
                        hlB[(size_t)r * DIM_ + oh * 256 + w * 64 + ot * 16 + ll] = f2bf(acc[mt][ot][reg]);
                }
    }
}

// ==== main: BM=128 x BN=512, BK=32 — round-6 schedule, 32x32x16 MFMA ========
// 8 waves (2M x 4N), wave tile 64x128, acc = f32x16[2][4] (128 AGPR).
// LDS 112KB: A 2x8KB dbuf + B 3x32KB triple-buf -> 1 block/CU.
// Per-iter wait: vmcnt(4) (prev tile's own 4 glds done, next tile's 4 stay
// in flight across the barrier) + lgkmcnt(0) (own packA ds_write drained).
__global__ __launch_bounds__(512, 2) void k_main2(
    const ushort* __restrict__ hlB, const float* __restrict__ hpb,
    const char* __restrict__ panel, const float* __restrict__ b2,
    const float* __restrict__ W3, const float* __restrict__ b3,
    float* __restrict__ out) {
    __shared__ f32x4 ldsv[7168];            // 114688 B
    char* lds = (char*)ldsv;
    const int t = threadIdx.x;
    const int n0 = blockIdx.x * 64, s0 = blockIdx.y * 2;
    const int w = t >> 6, lane = t & 63;
    const int l31 = lane & 31, hi = lane >> 5;
    const int wr = w >> 2, wc = w & 3;      // 2M x 4N wave grid

    // A-staging: thread t owns one 16B chunk (row = t>>2, kslot = t&3)
    const int arow = t >> 2, akslot = t & 3;
    int an = n0 + (arow & 63); if (an >= NL_) an = NL_ - 1;
    const ushort* hlsrc = hlB + (size_t)an * DIM_ + akslot * 8;
    const float*  hpsrc = hpb + (s0 + (arow >> 6)) * DIM_ + akslot * 8;
    const int awz = swz(arow, akslot);

    // 32x32x16 fragment offsets: A row = wr*64+mt*32+l31, B row = wc*128+ot*32+l31;
    // kslot = kh*2 + hi  (kh = K-half within the 32-wide k-tile)
    int aoffS[2][2], boffS[4][2];
#pragma unroll
    for (int mt = 0; mt < 2; mt++)
#pragma unroll
        for (int kh = 0; kh < 2; kh++)
            aoffS[mt][kh] = swz(wr * 64 + mt * 32 + l31, kh * 2 + hi);
#pragma unroll
    for (int ot = 0; ot < 4; ot++)
#pragma unroll
        for (int kh = 0; kh < 2; kh++)
            boffS[ot][kh] = swz(wc * 128 + ot * 32 + l31, kh * 2 + hi);

    f32x16 acc[2][4] = {};

    // B-stage: per wave 4 x 1KB chunks (4 glds/thread); LDS dest wave-uniform.
    auto stageB = [&](int kt, int buf) {
        const char* base = panel + kt * 32768 + w * 4096 + (lane << 4);
        char* ldsB = lds + 16384 + buf * 32768 + w * 4096;
#pragma unroll
        for (int r = 0; r < 4; r++) glds16(base + r * 1024, ldsB + r * 1024);
    };
    auto packA = [&](int buf, short8 hv, float4 p0, float4 p1) {
        float hp8[8] = { p0.x, p0.y, p0.z, p0.w, p1.x, p1.y, p1.z, p1.w };
        float x[8];
#pragma unroll
        for (int e = 0; e < 8; e++) {
            float s = bf2f((ushort)hv[e]) + hp8[e];
            x[e] = s > 0.f ? s : 0.f;
        }
        union { __hip_bfloat162 h2[4]; short8 v; } pk;
#pragma unroll
        for (int e = 0; e < 4; e++)
            pk.h2[e] = __float22bfloat162_rn(make_float2(x[2 * e], x[2 * e + 1]));
        *(short8*)(lds + buf * 8192 + awz) = pk.v;
    };

    // ---- prologue: regs(0), stage(0), stage(1); packA(0); counted wait ----
    {
        short8 hv = *(const short8*)(hlsrc);
        float4 p0 = *(const float4*)(hpsrc);
        float4 p1 = *(const float4*)(hpsrc + 4);
        __builtin_amdgcn_sched_barrier(0);
        stageB(0, 0);
        stageB(1, 1);
        __builtin_amdgcn_sched_barrier(0);
        packA(0, hv, p0, p1);                 // auto-wait leaves stages in flight
        asm volatile("s_waitcnt vmcnt(4) lgkmcnt(0)" ::: "memory");
        __builtin_amdgcn_s_barrier();
    }

    for (int kt = 0; kt < KSTEPS; kt++) {
        short8 hv; float4 p0, p1;
        if (kt + 1 < KSTEPS) {                // reg loads FIRST so packA's
            hv = *(const short8*)(hlsrc + (kt + 1) * BK);   // auto-wait is
            p0 = *(const float4*)(hpsrc + (kt + 1) * BK);   // counted, not 0
            p1 = *(const float4*)(hpsrc + (kt + 1) * BK + 4);
        }
        __builtin_amdgcn_sched_barrier(0);
        if (kt + 2 < KSTEPS) stageB(kt + 2, (kt + 2) % 3);  // 2-deep prefetch
        __builtin_amdgcn_sched_barrier(0);
        const char* A = lds + (kt & 1) * 8192;
        const char* B = lds + 16384 + (kt % 3) * 32768;
        short8 a[2][2], b[4][2];
#pragma unroll
        for (int mt = 0; mt < 2; mt++)
#pragma unroll
            for (int kh = 0; kh < 2; kh++)
                a[mt][kh] = *(const short8*)(A + aoffS[mt][kh]);
#pragma unroll
        for (int ot = 0; ot < 4; ot++)
#pragma unroll
            for (int kh = 0; kh < 2; kh++)
                b[ot][kh] = *(const short8*)(B + boffS[ot][kh]);
        __builtin_amdgcn_s_setprio(1);
#pragma unroll
        for (int kh = 0; kh < 2; kh++)
#pragma unroll
            for (int mt = 0; mt < 2; mt++)
#pragma unroll
                for (int ot = 0; ot < 4; ot++)
                    acc[mt][ot] = __builtin_amdgcn_mfma_f32_32x32x16_bf16(
                        a[mt][kh], b[ot][kh], acc[mt][ot], 0, 0, 0);
        __builtin_amdgcn_s_setprio(0);
        if (kt + 1 < KSTEPS) packA((kt + 1) & 1, hv, p0, p1);
        // own prev-tile glds done (next tile's 4 stay in flight) + own
        // packA ds_write drained; barrier makes it block-wide.
        asm volatile("s_waitcnt vmcnt(4) lgkmcnt(0)" ::: "memory");
        __builtin_amdgcn_s_barrier();
    }

    // ---- epilogue: relu(acc+b2)*W3, reduce over o; direct out write ----
    // 32x32 C/D map (m74/m101): col = lane&31, row = (reg&3)+8*(reg>>2)+4*hi
    float* logit = (float*)lds;                           // reuse A buf 0
    if (t < 128) logit[t] = 0.f;
    __syncthreads();
#pragma unroll
    for (int mt = 0; mt < 2; mt++) {
        float p16[16];
#pragma unroll
        for (int reg = 0; reg < 16; reg++) p16[reg] = 0.f;
#pragma unroll
        for (int ot = 0; ot < 4; ot++) {
            int o = wc * 128 + ot * 32 + l31;
            float bb = b2[o], w3 = W3[o];
#pragma unroll
            for (int reg = 0; reg < 16; reg++) {
                float v = acc[mt][ot][reg] + bb;
                v = v > 0.f ? v : 0.f;
                p16[reg] += v * w3;
            }
        }
#pragma unroll
        for (int m = 1; m < 32; m <<= 1)
#pragma unroll
            for (int reg = 0; reg < 16; reg++) p16[reg] += __shfl_xor(p16[reg], m, 64);
        if (l31 == 0) {
#pragma unroll
            for (int reg = 0; reg < 16; reg++) {
                int row = wr * 64 + mt * 32 + (reg & 3) + 8 * (reg >> 2) + 4 * hi;
                atomicAdd(&logit[row], p16[reg]);
            }
        }
    }
    __syncthreads();
    if (t < 128) {
        int n = n0 + (t & 63);
        int s = s0 + (t >> 6);
        if (n < NL_) out[(size_t)s * NL_ + n] = logit[t] + b3[0];
    }
}

extern "C" void kernel_launch(void* const* d_in, const int* in_sizes, int n_in,
                              void* d_out, int out_size, void* d_ws, size_t ws_size,
                              hipStream_t stream) {
    const float* P_f = (const float*)d_in[0];
    const float* emb = (const float*)d_in[1];
    const float* W_p = (const float*)d_in[2];
    const float* W_l = (const float*)d_in[3];
    const float* W1  = (const float*)d_in[4];
    const float* b1  = (const float*)d_in[5];
    const float* W2  = (const float*)d_in[6];
    const float* b2  = (const float*)d_in[7];
    const float* W3  = (const float*)d_in[8];
    const float* b3  = (const float*)d_in[9];
    const int*   L   = (const int*)d_in[10];
    float* out = (float*)d_out;

    char* ws = (char*)d_ws;
    size_t off = 0;
    auto alloc = [&](size_t bytes) {
        void* p = ws + off;
        off = (off + bytes + 255) & ~(size_t)255;
        return p;
    };
    char*   panel = (char*)alloc((size_t)KSTEPS * 32768);            // 512 KB
    ushort* MlT   = (ushort*)alloc((size_t)OD_ * LD_ * 2);           // 768 KB
    float*  P_e   = (float*)alloc((size_t)S_ * DIM_ * 4);
    float*  hpb   = (float*)alloc((size_t)S_ * DIM_ * 4);
    ushort* hlB   = (ushort*)alloc((size_t)NL_ * DIM_ * 2);          // 5.12 MB

    k_pre1<<<832, 256, 0, stream>>>(W2, W_l, W1, P_f, W_p, panel, MlT, P_e);
    k_pre2<<<826, 256, 0, stream>>>(P_e, W1, b1, emb, L, MlT, hpb, hlB);
    k_main2<<<dim3(NT_M, 32), 512, 0, stream>>>(hlB, hpb, panel, b2, W3, b3, out);
}

// Round 9
// 275.705 us; speedup vs baseline: 1.2354x; 1.2307x over previous
//
#include <hip/hip_runtime.h>
#include <hip/hip_bf16.h>

typedef short short8 __attribute__((ext_vector_type(8)));
typedef float f32x4 __attribute__((ext_vector_type(4)));

#define S_   64
#define NL_  5000
#define PD_  1024
#define LD_  768
#define DIM_ 512
#define OD_  512

#define BK     32
#define KSTEPS 16          // DIM_/BK
#define NT_M   79          // ceil(5000/64) n-tiles for main
#define HL_RT  157         // ceil(5000/32) row-tiles for hl

__device__ __forceinline__ ushort f2bf(float f) {
    union { float f; unsigned u; } v; v.f = f;
    unsigned r = v.u + 0x7fffu + ((v.u >> 16) & 1u);   // RNE
    return (ushort)(r >> 16);
}
__device__ __forceinline__ float bf2f(ushort h) {
    union { unsigned u; float f; } v; v.u = ((unsigned)h) << 16;
    return v.f;
}
// XOR swizzle for 64B-stride row tiles: conflict-free for packA write
// (4 lanes/row x 4 kslots) and the 16-row x 4-kslot read (measured 0
// conflicts in r6). NOT valid for 32-row reads (r8: 1.5e7 conflicts).
__device__ __forceinline__ int swz(int row, int kslot) {
    return (row * 64 + kslot * 16) ^ (((row >> 1) & 7) << 4);
}
__device__ __forceinline__ void glds16(const void* g, void* l) {
    __builtin_amdgcn_global_load_lds(
        (const __attribute__((address_space(1))) void*)g,
        (__attribute__((address_space(3))) void*)l, 16, 0, 0);
}

// ---- coalesced small GEMM: C[s][o0..o0+7] = A[64][K] @ W[.][K]^T (+bias) ---
// 256 threads. A staged in LDS in 256-col chunks (rows loaded contiguously,
// 1KB per 4 lanes -> fully coalesced). Thread (s = t&63, og = t>>6) owns
// o = o0 + og*2 + {0,1}. LDS reads 2-way bank (free); W reads broadcast.
__device__ __forceinline__ void proj8(
    float* Af /* [64][258] */, const float* __restrict__ A, int lda, int K,
    const float* __restrict__ W, int ldw, const float* __restrict__ bias,
    float* __restrict__ C, int o0, int t) {
    const int s = t & 63, og = t >> 6;
    const int oA = o0 + og * 2, oB = oA + 1;
    float acc0 = 0.f, acc1 = 0.f;
    for (int ck = 0; ck < K; ck += 256) {
        __syncthreads();
        // stage: 16 insts, each 4 full rows of the 256-col chunk
#pragma unroll
        for (int it = 0; it < 16; it++) {
            int r = it * 4 + (t >> 6);
            float4 v = *(const float4*)(A + (size_t)r * lda + ck + (t & 63) * 4);
            *(float4*)(Af + r * 258 + (t & 63) * 4) = v;
        }
        __syncthreads();
        const float* w0 = W + (size_t)oA * ldw + ck;
        const float* w1 = W + (size_t)oB * ldw + ck;
        const float* ar = Af + s * 258;
#pragma unroll 8
        for (int k4 = 0; k4 < 64; k4++) {
            f32x4 a4 = *(const f32x4*)(ar + k4 * 4);
            float4 v0 = *(const float4*)(w0 + k4 * 4);
            float4 v1 = *(const float4*)(w1 + k4 * 4);
            acc0 += a4[0] * v0.x + a4[1] * v0.y + a4[2] * v0.z + a4[3] * v0.w;
            acc1 += a4[0] * v1.x + a4[1] * v1.y + a4[2] * v1.z + a4[3] * v1.w;
        }
    }
    C[s * DIM_ + oA] = acc0 + (bias ? bias[oA] : 0.f);
    C[s * DIM_ + oB] = acc1 + (bias ? bias[oB] : 0.f);
}

// ==== pre-pass 1: {W2 panel | M_lT fold | P_e = P_f @ W_p.T} ================
// blocks: 0..127 panel, 128..319 mlt, 320..383 P_e (8 o-cols each).
__global__ __launch_bounds__(256) void k_pre1(
    const float* __restrict__ W2, const float* __restrict__ W_l,
    const float* __restrict__ W1, const float* __restrict__ P_f,
    const float* __restrict__ W_p,
    char* __restrict__ panel, ushort* __restrict__ MlT, float* __restrict__ P_e) {
    __shared__ float lbuf[64 * 258];       // 66048 B (union: w1r uses 16KB)
    int b = blockIdx.x, t = threadIdx.x;
    if (b < 128) {
        int c = b * 256 + t;                   // 32768 16B-chunks
        int o = c >> 6, rem = c & 63, kt = rem >> 2, kslot = rem & 3;
        const float* src = W2 + o * DIM_ + kt * BK + kslot * 8;
        float4 v0 = *(const float4*)src;
        float4 v1 = *(const float4*)(src + 4);
        union { ushort u[8]; short8 v; } pk;
        pk.u[0] = f2bf(v0.x); pk.u[1] = f2bf(v0.y); pk.u[2] = f2bf(v0.z); pk.u[3] = f2bf(v0.w);
        pk.u[4] = f2bf(v1.x); pk.u[5] = f2bf(v1.y); pk.u[6] = f2bf(v1.z); pk.u[7] = f2bf(v1.w);
        *(short8*)(panel + kt * 32768 + swz(o, kslot)) = pk.v;
    } else if (b < 320) {
        float (*w1r)[DIM_] = (float (*)[DIM_])lbuf;
        int bx = b - 128;
        int o0 = (bx / 3) * 8;
        int ld = (bx % 3) * 256 + t;
        for (int i = t; i < 8 * DIM_; i += 256)
            w1r[i >> 9][i & 511] = W1[(o0 + (i >> 9)) * (2 * DIM_) + DIM_ + (i & 511)];
        __syncthreads();
        float acc[8] = {};
        for (int dim = 0; dim < DIM_; dim++) {
            float wl = W_l[dim * LD_ + ld];
#pragma unroll
            for (int oi = 0; oi < 8; oi++) acc[oi] += w1r[oi][dim] * wl;
        }
#pragma unroll
        for (int oi = 0; oi < 8; oi++) MlT[(o0 + oi) * LD_ + ld] = f2bf(acc[oi]);
    } else {
        proj8(lbuf, P_f, PD_, PD_, W_p, PD_, nullptr, P_e, (b - 320) * 8, t);
    }
}

// ==== pre-pass 2: {hpb = P_e @ W1p.T + b1 | hlB = bf16(emb[L]) @ MlT} =======
// blocks: 0..63 hp (8 o-cols each), 64..377 hl.
__global__ __launch_bounds__(256) void k_pre2(
    const float* __restrict__ P_e, const float* __restrict__ W1,
    const float* __restrict__ b1, const float* __restrict__ emb,
    const int* __restrict__ L, const ushort* __restrict__ MlT,
    float* __restrict__ hpb, ushort* __restrict__ hlB) {
    __shared__ float lbuf[64 * 258];
    int b = blockIdx.x, t = threadIdx.x;
    if (b < 64) {
        proj8(lbuf, P_e, DIM_, DIM_, W1, 2 * DIM_, b1, hpb, b * 8, t);
    } else {
        int hb = b - 64;                      // 0..313
        int rblk = hb % HL_RT, oh = hb / HL_RT;
        int r0 = rblk * 32;
        int w = t >> 6, l = t & 63, lg = l >> 4, ll = l & 15;
        const float* arow[2];
#pragma unroll
        for (int mt = 0; mt < 2; mt++) {
            int r = r0 + mt * 16 + ll;
            if (r >= NL_) r = NL_ - 1;
            arow[mt] = emb + (size_t)L[r] * LD_ + lg * 8;
        }
        f32x4 acc[2][4] = {};
        for (int k = 0; k < LD_; k += 32) {
            short8 a[2], bf[4];
#pragma unroll
            for (int mt = 0; mt < 2; mt++) {
                float4 v0 = *(const float4*)(arow[mt] + k);
                float4 v1 = *(const float4*)(arow[mt] + k + 4);
                union { ushort u[8]; short8 v; } pk;
                pk.u[0] = f2bf(v0.x); pk.u[1] = f2bf(v0.y);
                pk.u[2] = f2bf(v0.z); pk.u[3] = f2bf(v0.w);
                pk.u[4] = f2bf(v1.x); pk.u[5] = f2bf(v1.y);
                pk.u[6] = f2bf(v1.z); pk.u[7] = f2bf(v1.w);
                a[mt] = pk.v;
            }
#pragma unroll
            for (int ot = 0; ot < 4; ot++) {
                int o = oh * 256 + w * 64 + ot * 16 + ll;
                bf[ot] = *(const short8*)(MlT + o * LD_ + k + lg * 8);
            }
#pragma unroll
            for (int mt = 0; mt < 2; mt++)
#pragma unroll
                for (int ot = 0; ot < 4; ot++)
                    acc[mt][ot] = __builtin_amdgcn_mfma_f32_16x16x32_bf16(a[mt], bf[ot], acc[mt][ot], 0, 0, 0);
        }
#pragma unroll
        for (int mt = 0; mt < 2; mt++)
#pragma unroll
            for (int ot = 0; ot < 4; ot++)
#pragma unroll
                for (int reg = 0; reg < 4; reg++) {
                    int r = r0 + mt * 16 + lg * 4 + reg;
                    if (r < NL_)
                        hlB[(size_t)r * DIM_ + oh * 256 + w * 64 + ot * 16 + ll] = f2bf(acc[mt][ot][reg]);
                }
    }
}

// ==== main: BM=128 x BN=512, BK=32, counted-vmcnt pipeline (round-6 best) ===
// 8 waves (2M x 4N), wave tile 64x128, acc[4][8] (AGPR). VGPR=112, no spill.
// LDS 112KB: A 2x8KB dbuf + B 3x32KB triple-buf -> 1 block/CU.
// Per-iter wait: vmcnt(4) (prev tile's own 4 glds done, next tile's 4 stay
// in flight across the barrier) + lgkmcnt(0) (own packA ds_write drained).
__global__ __launch_bounds__(512, 2) void k_main2(
    const ushort* __restrict__ hlB, const float* __restrict__ hpb,
    const char* __restrict__ panel, const float* __restrict__ b2,
    const float* __restrict__ W3, const float* __restrict__ b3,
    float* __restrict__ out) {
    __shared__ f32x4 ldsv[7168];            // 114688 B
    char* lds = (char*)ldsv;
    const int t = threadIdx.x;
    const int n0 = blockIdx.x * 64, s0 = blockIdx.y * 2;
    const int w = t >> 6, lane = t & 63, lg = lane >> 4, ll = lane & 15;
    const int wr = w >> 2, wc = w & 3;      // 2M x 4N wave grid

    // A-staging: thread t owns one 16B chunk (row = t>>2, kslot = t&3)
    const int arow = t >> 2, akslot = t & 3;
    int an = n0 + (arow & 63); if (an >= NL_) an = NL_ - 1;
    const ushort* hlsrc = hlB + (size_t)an * DIM_ + akslot * 8;
    const float*  hpsrc = hpb + (s0 + (arow >> 6)) * DIM_ + akslot * 8;
    const int awz = swz(arow, akslot);

    int aoffS[4], boffS[8];
#pragma unroll
    for (int mt = 0; mt < 4; mt++) aoffS[mt] = swz(wr * 64 + mt * 16 + ll, lg);
#pragma unroll
    for (int ot = 0; ot < 8; ot++) boffS[ot] = swz(wc * 128 + ot * 16 + ll, lg);

    f32x4 acc[4][8] = {};

    // B-stage: per wave 4 x 1KB chunks (4 glds/thread); LDS dest wave-uniform.
    auto stageB = [&](int kt, int buf) {
        const char* base = panel + kt * 32768 + w * 4096 + (lane << 4);
        char* ldsB = lds + 16384 + buf * 32768 + w * 4096;
#pragma unroll
        for (int r = 0; r < 4; r++) glds16(base + r * 1024, ldsB + r * 1024);
    };
    auto packA = [&](int buf, short8 hv, float4 p0, float4 p1) {
        float hp8[8] = { p0.x, p0.y, p0.z, p0.w, p1.x, p1.y, p1.z, p1.w };
        float x[8];
#pragma unroll
        for (int e = 0; e < 8; e++) {
            float s = bf2f((ushort)hv[e]) + hp8[e];
            x[e] = s > 0.f ? s : 0.f;
        }
        union { __hip_bfloat162 h2[4]; short8 v; } pk;
#pragma unroll
        for (int e = 0; e < 4; e++)
            pk.h2[e] = __float22bfloat162_rn(make_float2(x[2 * e], x[2 * e + 1]));
        *(short8*)(lds + buf * 8192 + awz) = pk.v;
    };

    // ---- prologue: regs(0), stage(0), stage(1); packA(0); counted wait ----
    {
        short8 hv = *(const short8*)(hlsrc);
        float4 p0 = *(const float4*)(hpsrc);
        float4 p1 = *(const float4*)(hpsrc + 4);
        __builtin_amdgcn_sched_barrier(0);
        stageB(0, 0);
        stageB(1, 1);
        __builtin_amdgcn_sched_barrier(0);
        packA(0, hv, p0, p1);                 // auto-wait leaves stages in flight
        asm volatile("s_waitcnt vmcnt(4) lgkmcnt(0)" ::: "memory");
        __builtin_amdgcn_s_barrier();
    }

    for (int kt = 0; kt < KSTEPS; kt++) {
        short8 hv; float4 p0, p1;
        if (kt + 1 < KSTEPS) {                // reg loads FIRST so packA's
            hv = *(const short8*)(hlsrc + (kt + 1) * BK);   // auto-wait is
            p0 = *(const float4*)(hpsrc + (kt + 1) * BK);   // counted, not 0
            p1 = *(const float4*)(hpsrc + (kt + 1) * BK + 4);
        }
        __builtin_amdgcn_sched_barrier(0);
        if (kt + 2 < KSTEPS) stageB(kt + 2, (kt + 2) % 3);  // 2-deep prefetch
        __builtin_amdgcn_sched_barrier(0);
        const char* A = lds + (kt & 1) * 8192;
        const char* B = lds + 16384 + (kt % 3) * 32768;
        short8 a[4], b[8];
#pragma unroll
        for (int mt = 0; mt < 4; mt++) a[mt] = *(const short8*)(A + aoffS[mt]);
#pragma unroll
        for (int ot = 0; ot < 8; ot++) b[ot] = *(const short8*)(B + boffS[ot]);
        __builtin_amdgcn_s_setprio(1);
#pragma unroll
        for (int mt = 0; mt < 4; mt++)
#pragma unroll
            for (int ot = 0; ot < 8; ot++)
                acc[mt][ot] = __builtin_amdgcn_mfma_f32_16x16x32_bf16(a[mt], b[ot], acc[mt][ot], 0, 0, 0);
        __builtin_amdgcn_s_setprio(0);
        if (kt + 1 < KSTEPS) packA((kt + 1) & 1, hv, p0, p1);
        // own prev-tile glds done (next tile's 4 stay in flight) + own
        // packA ds_write drained; barrier makes it block-wide.
        asm volatile("s_waitcnt vmcnt(4) lgkmcnt(0)" ::: "memory");
        __builtin_amdgcn_s_barrier();
    }

    // ---- epilogue: relu(acc+b2)*W3, reduce over o; direct out write ----
    float* logit = (float*)lds;                           // reuse A buf 0
    if (t < 128) logit[t] = 0.f;
    __syncthreads();
#pragma unroll
    for (int mt = 0; mt < 4; mt++) {
        float p4[4] = { 0.f, 0.f, 0.f, 0.f };
#pragma unroll
        for (int ot = 0; ot < 8; ot++) {
            int o = wc * 128 + ot * 16 + ll;
            float bb = b2[o], w3 = W3[o];
#pragma unroll
            for (int reg = 0; reg < 4; reg++) {
                float v = acc[mt][ot][reg] + bb;
                v = v > 0.f ? v : 0.f;
                p4[reg] += v * w3;
            }
        }
#pragma unroll
        for (int m = 1; m < 16; m <<= 1)
#pragma unroll
            for (int reg = 0; reg < 4; reg++) p4[reg] += __shfl_xor(p4[reg], m, 64);
        if (ll == 0)
#pragma unroll
            for (int reg = 0; reg < 4; reg++)
                atomicAdd(&logit[wr * 64 + mt * 16 + lg * 4 + reg], p4[reg]);
    }
    __syncthreads();
    if (t < 128) {
        int n = n0 + (t & 63);
        int s = s0 + (t >> 6);
        if (n < NL_) out[(size_t)s * NL_ + n] = logit[t] + b3[0];
    }
}

extern "C" void kernel_launch(void* const* d_in, const int* in_sizes, int n_in,
                              void* d_out, int out_size, void* d_ws, size_t ws_size,
                              hipStream_t stream) {
    const float* P_f = (const float*)d_in[0];
    const float* emb = (const float*)d_in[1];
    const float* W_p = (const float*)d_in[2];
    const float* W_l = (const float*)d_in[3];
    const float* W1  = (const float*)d_in[4];
    const float* b1  = (const float*)d_in[5];
    const float* W2  = (const float*)d_in[6];
    const float* b2  = (const float*)d_in[7];
    const float* W3  = (const float*)d_in[8];
    const float* b3  = (const float*)d_in[9];
    const int*   L   = (const int*)d_in[10];
    float* out = (float*)d_out;

    char* ws = (char*)d_ws;
    size_t off = 0;
    auto alloc = [&](size_t bytes) {
        void* p = ws + off;
        off = (off + bytes + 255) & ~(size_t)255;
        return p;
    };
    char*   panel = (char*)alloc((size_t)KSTEPS * 32768);            // 512 KB
    ushort* MlT   = (ushort*)alloc((size_t)OD_ * LD_ * 2);           // 768 KB
    float*  P_e   = (float*)alloc((size_t)S_ * DIM_ * 4);
    float*  hpb   = (float*)alloc((size_t)S_ * DIM_ * 4);
    ushort* hlB   = (ushort*)alloc((size_t)NL_ * DIM_ * 2);          // 5.12 MB

    k_pre1<<<384, 256, 0, stream>>>(W2, W_l, W1, P_f, W_p, panel, MlT, P_e);
    k_pre2<<<378, 256, 0, stream>>>(P_e, W1, b1, emb, L, MlT, hpb, hlB);
    k_main2<<<dim3(NT_M, 32), 512, 0, stream>>>(hlB, hpb, panel, b2, W3, b3, out);
}

// Round 10
// 273.523 us; speedup vs baseline: 1.2453x; 1.0080x over previous
//
#include <hip/hip_runtime.h>
#include <hip/hip_bf16.h>

typedef short short8 __attribute__((ext_vector_type(8)));
typedef float f32x4 __attribute__((ext_vector_type(4)));

#define S_   64
#define NL_  5000
#define PD_  1024
#define LD_  768
#define DIM_ 512
#define OD_  512

#define BK     32
#define KSTEPS 16          // DIM_/BK
#define NT_M   79          // ceil(5000/64) n-tiles for main
#define HL_RT  157         // ceil(5000/32) row-tiles for hl

__device__ __forceinline__ ushort f2bf(float f) {
    union { float f; unsigned u; } v; v.f = f;
    unsigned r = v.u + 0x7fffu + ((v.u >> 16) & 1u);   // RNE
    return (ushort)(r >> 16);
}
__device__ __forceinline__ float bf2f(ushort h) {
    union { unsigned u; float f; } v; v.u = ((unsigned)h) << 16;
    return v.f;
}
// XOR swizzle for the A tile (64B-stride rows): conflict-free for packA write
// (4 lanes/row x 4 kslots) and the 16-row x 4-kslot fragment read (measured 0
// conflicts r6/r9). swz(row+16,k) == swz(row,k)+1024 (XOR bits 4..6 invariant
// under row+16), so all 4 A-fragments fold to one base + imm offset.
__device__ __forceinline__ int swz(int row, int kslot) {
    return (row * 64 + kslot * 16) ^ (((row >> 1) & 7) << 4);
}

// ---- coalesced small GEMM: C[s][o0..o0+7] = A[64][K] @ W[.][K]^T (+bias) ---
__device__ __forceinline__ void proj8(
    float* Af /* [64][258] */, const float* __restrict__ A, int lda, int K,
    const float* __restrict__ W, int ldw, const float* __restrict__ bias,
    float* __restrict__ C, int o0, int t) {
    const int s = t & 63, og = t >> 6;
    const int oA = o0 + og * 2, oB = oA + 1;
    float acc0 = 0.f, acc1 = 0.f;
    for (int ck = 0; ck < K; ck += 256) {
        __syncthreads();
#pragma unroll
        for (int it = 0; it < 16; it++) {
            int r = it * 4 + (t >> 6);
            float4 v = *(const float4*)(A + (size_t)r * lda + ck + (t & 63) * 4);
            *(float4*)(Af + r * 258 + (t & 63) * 4) = v;
        }
        __syncthreads();
        const float* w0 = W + (size_t)oA * ldw + ck;
        const float* w1 = W + (size_t)oB * ldw + ck;
        const float* ar = Af + s * 258;
#pragma unroll 8
        for (int k4 = 0; k4 < 64; k4++) {
            f32x4 a4 = *(const f32x4*)(ar + k4 * 4);
            float4 v0 = *(const float4*)(w0 + k4 * 4);
            float4 v1 = *(const float4*)(w1 + k4 * 4);
            acc0 += a4[0] * v0.x + a4[1] * v0.y + a4[2] * v0.z + a4[3] * v0.w;
            acc1 += a4[0] * v1.x + a4[1] * v1.y + a4[2] * v1.z + a4[3] * v1.w;
        }
    }
    C[s * DIM_ + oA] = acc0 + (bias ? bias[oA] : 0.f);
    C[s * DIM_ + oB] = acc1 + (bias ? bias[oB] : 0.f);
}

// ==== pre-pass 1: {W2 panel (MFMA-fragment order) | M_lT | P_e} =============
// Panel layout: per kt (32KB), per o-group og=o>>4 (1KB), lane l=lg*16+ll at
// +l*16 -> in-loop B fragment read = one fully-coalesced 1KB per (wave,frag).
__global__ __launch_bounds__(256) void k_pre1(
    const float* __restrict__ W2, const float* __restrict__ W_l,
    const float* __restrict__ W1, const float* __restrict__ P_f,
    const float* __restrict__ W_p,
    char* __restrict__ panel, ushort* __restrict__ MlT, float* __restrict__ P_e) {
    __shared__ float lbuf[64 * 258];       // 66048 B (union: w1r uses 16KB)
    int b = blockIdx.x, t = threadIdx.x;
    if (b < 128) {
        int c = b * 256 + t;                   // 32768 16B-chunks
        int o = c >> 6, rem = c & 63, kt = rem >> 2, kslot = rem & 3;
        const float* src = W2 + o * DIM_ + kt * BK + kslot * 8;
        float4 v0 = *(const float4*)src;
        float4 v1 = *(const float4*)(src + 4);
        union { ushort u[8]; short8 v; } pk;
        pk.u[0] = f2bf(v0.x); pk.u[1] = f2bf(v0.y); pk.u[2] = f2bf(v0.z); pk.u[3] = f2bf(v0.w);
        pk.u[4] = f2bf(v1.x); pk.u[5] = f2bf(v1.y); pk.u[6] = f2bf(v1.z); pk.u[7] = f2bf(v1.w);
        // fragment order: lane = kslot*16 + (o&15)
        *(short8*)(panel + kt * 32768 + (o >> 4) * 1024 + kslot * 256 + (o & 15) * 16) = pk.v;
    } else if (b < 320) {
        float (*w1r)[DIM_] = (float (*)[DIM_])lbuf;
        int bx = b - 128;
        int o0 = (bx / 3) * 8;
        int ld = (bx % 3) * 256 + t;
        for (int i = t; i < 8 * DIM_; i += 256)
            w1r[i >> 9][i & 511] = W1[(o0 + (i >> 9)) * (2 * DIM_) + DIM_ + (i & 511)];
        __syncthreads();
        float acc[8] = {};
        for (int dim = 0; dim < DIM_; dim++) {
            float wl = W_l[dim * LD_ + ld];
#pragma unroll
            for (int oi = 0; oi < 8; oi++) acc[oi] += w1r[oi][dim] * wl;
        }
#pragma unroll
        for (int oi = 0; oi < 8; oi++) MlT[(o0 + oi) * LD_ + ld] = f2bf(acc[oi]);
    } else {
        proj8(lbuf, P_f, PD_, PD_, W_p, PD_, nullptr, P_e, (b - 320) * 8, t);
    }
}

// ==== pre-pass 2: {hpb = P_e @ W1p.T + b1 | hlB = bf16(emb[L]) @ MlT} =======
__global__ __launch_bounds__(256) void k_pre2(
    const float* __restrict__ P_e, const float* __restrict__ W1,
    const float* __restrict__ b1, const float* __restrict__ emb,
    const int* __restrict__ L, const ushort* __restrict__ MlT,
    float* __restrict__ hpb, ushort* __restrict__ hlB) {
    __shared__ float lbuf[64 * 258];
    int b = blockIdx.x, t = threadIdx.x;
    if (b < 64) {
        proj8(lbuf, P_e, DIM_, DIM_, W1, 2 * DIM_, b1, hpb, b * 8, t);
    } else {
        int hb = b - 64;                      // 0..313
        int rblk = hb % HL_RT, oh = hb / HL_RT;
        int r0 = rblk * 32;
        int w = t >> 6, l = t & 63, lg = l >> 4, ll = l & 15;
        const float* arow[2];
#pragma unroll
        for (int mt = 0; mt < 2; mt++) {
            int r = r0 + mt * 16 + ll;
            if (r >= NL_) r = NL_ - 1;
            arow[mt] = emb + (size_t)L[r] * LD_ + lg * 8;
        }
        f32x4 acc[2][4] = {};
        for (int k = 0; k < LD_; k += 32) {
            short8 a[2], bf[4];
#pragma unroll
            for (int mt = 0; mt < 2; mt++) {
                float4 v0 = *(const float4*)(arow[mt] + k);
                float4 v1 = *(const float4*)(arow[mt] + k + 4);
                union { ushort u[8]; short8 v; } pk;
                pk.u[0] = f2bf(v0.x); pk.u[1] = f2bf(v0.y);
                pk.u[2] = f2bf(v0.z); pk.u[3] = f2bf(v0.w);
                pk.u[4] = f2bf(v1.x); pk.u[5] = f2bf(v1.y);
                pk.u[6] = f2bf(v1.z); pk.u[7] = f2bf(v1.w);
                a[mt] = pk.v;
            }
#pragma unroll
            for (int ot = 0; ot < 4; ot++) {
                int o = oh * 256 + w * 64 + ot * 16 + ll;
                bf[ot] = *(const short8*)(MlT + o * LD_ + k + lg * 8);
            }
#pragma unroll
            for (int mt = 0; mt < 2; mt++)
#pragma unroll
                for (int ot = 0; ot < 4; ot++)
                    acc[mt][ot] = __builtin_amdgcn_mfma_f32_16x16x32_bf16(a[mt], bf[ot], acc[mt][ot], 0, 0, 0);
        }
#pragma unroll
        for (int mt = 0; mt < 2; mt++)
#pragma unroll
            for (int ot = 0; ot < 4; ot++)
#pragma unroll
                for (int reg = 0; reg < 4; reg++) {
                    int r = r0 + mt * 16 + lg * 4 + reg;
                    if (r < NL_)
                        hlB[(size_t)r * DIM_ + oh * 256 + w * 64 + ot * 16 + ll] = f2bf(acc[mt][ot][reg]);
                }
    }
}

// ==== main: BM=128 x BN=512, BK=32 — B direct-from-L2 in registers ==========
// 8 waves (2M x 4N), wave tile 64x128, acc[4][8] (128 AGPR).
// B: fragment-ordered panel -> each frag = coalesced 1KB register load; quad
// double-buffer bq0/bq1 (32 VGPR), compiler-pipelined, NO barrier/LDS for B.
// A: 16KB LDS dbuf, packA shared by 4 N-waves; the only per-k-step sync is
// lgkmcnt(0)+barrier for the A dbuf. No manual vmcnt anywhere.
__global__ __launch_bounds__(512, 2) void k_main2(
    const ushort* __restrict__ hlB, const float* __restrict__ hpb,
    const char* __restrict__ panel, const float* __restrict__ b2,
    const float* __restrict__ W3, const float* __restrict__ b3,
    float* __restrict__ out) {
    __shared__ f32x4 ldsv[1024];            // 16384 B: A dbuf 2x8KB
    char* lds = (char*)ldsv;
    const int t = threadIdx.x;
    const int n0 = blockIdx.x * 64, s0 = blockIdx.y * 2;
    const int w = t >> 6, lane = t & 63, lg = lane >> 4, ll = lane & 15;
    const int wr = w >> 2, wc = w & 3;      // 2M x 4N wave grid

    // A-staging: thread t owns one 16B chunk (row = t>>2, kslot = t&3)
    const int arow = t >> 2, akslot = t & 3;
    int an = n0 + (arow & 63); if (an >= NL_) an = NL_ - 1;
    const ushort* hlsrc = hlB + (size_t)an * DIM_ + akslot * 8;
    const float*  hpsrc = hpb + (s0 + (arow >> 6)) * DIM_ + akslot * 8;
    const int awz = swz(arow, akslot);

    // A-frag: one base + mt*1024 imm; B: per-lane global base
    const int abase = swz(wr * 64 + ll, lg);
    const char* bbase = panel + (wc * 8) * 1024 + lane * 16;

    f32x4 acc[4][8] = {};

    auto packA = [&](int buf, short8 hv, float4 p0, float4 p1) {
        float hp8[8] = { p0.x, p0.y, p0.z, p0.w, p1.x, p1.y, p1.z, p1.w };
        float x[8];
#pragma unroll
        for (int e = 0; e < 8; e++) {
            float s = bf2f((ushort)hv[e]) + hp8[e];
            x[e] = s > 0.f ? s : 0.f;
        }
        union { __hip_bfloat162 h2[4]; short8 v; } pk;
#pragma unroll
        for (int e = 0; e < 4; e++)
            pk.h2[e] = __float22bfloat162_rn(make_float2(x[2 * e], x[2 * e + 1]));
        *(short8*)(lds + buf * 8192 + awz) = pk.v;
    };

    // ---- prologue: pack A(0); preload B quad (0,0) ----
    {
        short8 hv = *(const short8*)(hlsrc);
        float4 p0 = *(const float4*)(hpsrc);
        float4 p1 = *(const float4*)(hpsrc + 4);
        packA(0, hv, p0, p1);
        asm volatile("s_waitcnt lgkmcnt(0)" ::: "memory");
        __builtin_amdgcn_s_barrier();
    }
    short8 bq0[4], bq1[4];
#pragma unroll
    for (int j = 0; j < 4; j++) bq0[j] = *(const short8*)(bbase + j * 1024);

    for (int kt = 0; kt < KSTEPS; kt++) {
        const char* bkt = bbase + kt * 32768;
        short8 hv; float4 p0, p1;
        if (kt + 1 < KSTEPS) {                // next A inputs (latency-hidden)
            hv = *(const short8*)(hlsrc + (kt + 1) * BK);
            p0 = *(const float4*)(hpsrc + (kt + 1) * BK);
            p1 = *(const float4*)(hpsrc + (kt + 1) * BK + 4);
        }
        // A fragments for this k-step (buf kt&1, written 1 barrier ago)
        const char* A = lds + (kt & 1) * 8192;
        short8 a[4];
#pragma unroll
        for (int mt = 0; mt < 4; mt++) a[mt] = *(const short8*)(A + abase + mt * 1024);
        // issue quad (kt,1) while computing quad (kt,0)
#pragma unroll
        for (int j = 0; j < 4; j++) bq1[j] = *(const short8*)(bkt + 4096 + j * 1024);
        __builtin_amdgcn_s_setprio(1);
#pragma unroll
        for (int mt = 0; mt < 4; mt++)
#pragma unroll
            for (int j = 0; j < 4; j++)
                acc[mt][j] = __builtin_amdgcn_mfma_f32_16x16x32_bf16(a[mt], bq0[j], acc[mt][j], 0, 0, 0);
        __builtin_amdgcn_s_setprio(0);
        // issue quad (kt+1,0) while computing quad (kt,1)
        if (kt + 1 < KSTEPS)
#pragma unroll
            for (int j = 0; j < 4; j++) bq0[j] = *(const short8*)(bkt + 32768 + j * 1024);
        __builtin_amdgcn_s_setprio(1);
#pragma unroll
        for (int mt = 0; mt < 4; mt++)
#pragma unroll
            for (int j = 0; j < 4; j++)
                acc[mt][4 + j] = __builtin_amdgcn_mfma_f32_16x16x32_bf16(a[mt], bq1[j], acc[mt][4 + j], 0, 0, 0);
        __builtin_amdgcn_s_setprio(0);
        if (kt + 1 < KSTEPS) packA((kt + 1) & 1, hv, p0, p1);
        // A dbuf sync only: all ds ops (reads of buf kt&1, write of buf
        // (kt+1)&1) drained, then block-wide barrier.
        asm volatile("s_waitcnt lgkmcnt(0)" ::: "memory");
        __builtin_amdgcn_s_barrier();
    }

    // ---- epilogue: relu(acc+b2)*W3, reduce over o; direct out write ----
    float* logit = (float*)lds;
    if (t < 128) logit[t] = 0.f;
    __syncthreads();
#pragma unroll
    for (int mt = 0; mt < 4; mt++) {
        float p4[4] = { 0.f, 0.f, 0.f, 0.f };
#pragma unroll
        for (int ot = 0; ot < 8; ot++) {
            int o = wc * 128 + ot * 16 + ll;
            float bb = b2[o], w3 = W3[o];
#pragma unroll
            for (int reg = 0; reg < 4; reg++) {
                float v = acc[mt][ot][reg] + bb;
                v = v > 0.f ? v : 0.f;
                p4[reg] += v * w3;
            }
        }
#pragma unroll
        for (int m = 1; m < 16; m <<= 1)
#pragma unroll
            for (int reg = 0; reg < 4; reg++) p4[reg] += __shfl_xor(p4[reg], m, 64);
        if (ll == 0)
#pragma unroll
            for (int reg = 0; reg < 4; reg++)
                atomicAdd(&logit[wr * 64 + mt * 16 + lg * 4 + reg], p4[reg]);
    }
    __syncthreads();
    if (t < 128) {
        int n = n0 + (t & 63);
        int s = s0 + (t >> 6);
        if (n < NL_) out[(size_t)s * NL_ + n] = logit[t] + b3[0];
    }
}

extern "C" void kernel_launch(void* const* d_in, const int* in_sizes, int n_in,
                              void* d_out, int out_size, void* d_ws, size_t ws_size,
                              hipStream_t stream) {
    const float* P_f = (const float*)d_in[0];
    const float* emb = (const float*)d_in[1];
    const float* W_p = (const float*)d_in[2];
    const float* W_l = (const float*)d_in[3];
    const float* W1  = (const float*)d_in[4];
    const float* b1  = (const float*)d_in[5];
    const float* W2  = (const float*)d_in[6];
    const float* b2  = (const float*)d_in[7];
    const float* W3  = (const float*)d_in[8];
    const float* b3  = (const float*)d_in[9];
    const int*   L   = (const int*)d_in[10];
    float* out = (float*)d_out;

    char* ws = (char*)d_ws;
    size_t off = 0;
    auto alloc = [&](size_t bytes) {
        void* p = ws + off;
        off = (off + bytes + 255) & ~(size_t)255;
        return p;
    };
    char*   panel = (char*)alloc((size_t)KSTEPS * 32768);            // 512 KB
    ushort* MlT   = (ushort*)alloc((size_t)OD_ * LD_ * 2);           // 768 KB
    float*  P_e   = (float*)alloc((size_t)S_ * DIM_ * 4);
    float*  hpb   = (float*)alloc((size_t)S_ * DIM_ * 4);
    ushort* hlB   = (ushort*)alloc((size_t)NL_ * DIM_ * 2);          // 5.12 MB

    k_pre1<<<384, 256, 0, stream>>>(W2, W_l, W1, P_f, W_p, panel, MlT, P_e);
    k_pre2<<<378, 256, 0, stream>>>(P_e, W1, b1, emb, L, MlT, hpb, hlB);
    k_main2<<<dim3(NT_M, 32), 512, 0, stream>>>(hlB, hpb, panel, b2, W3, b3, out);
}